// Round 3
// baseline (1315.064 us; speedup 1.0000x reference)
//
#include <hip/hip_runtime.h>
#include <hip/hip_bf16.h>
#include <math.h>

#define Bb 2
#define Nn 2048
#define Dd 512
#define Hh 16
#define DKk 32

// ---------------------------------------------------------------------------
// Kernel 1: fused QKV projection.
// X [4096 x 512] (q/k/v) times W [512 x 512] (proj per head, cols = h*32+dk)
// -> out [B,H,N,DK] (+bias).  Tile 128x64, K-step 32, 8x4 microtile/thread.
// ---------------------------------------------------------------------------
__global__ __launch_bounds__(256) void qkv_proj_kernel(
    const float* __restrict__ q, const float* __restrict__ k, const float* __restrict__ v,
    const float* __restrict__ q_proj, const float* __restrict__ k_proj, const float* __restrict__ v_proj,
    const float* __restrict__ q_bias, const float* __restrict__ k_bias, const float* __restrict__ v_bias,
    float* __restrict__ Qws, float* __restrict__ Kws, float* __restrict__ Vws)
{
    const int gz = blockIdx.z; // 0=q,1=k,2=v
    const float* __restrict__ X = (gz == 0) ? q : (gz == 1) ? k : v;
    const float* __restrict__ W = (gz == 0) ? q_proj : (gz == 1) ? k_proj : v_proj;
    const float* __restrict__ bias = (gz == 0) ? q_bias : (gz == 1) ? k_bias : v_bias;
    float* __restrict__ O = (gz == 0) ? Qws : (gz == 1) ? Kws : Vws;

    const int m0 = blockIdx.x * 128;
    const int c0 = blockIdx.y * 64;

    __shared__ float XsT[32][132];  // [kk][row], padded
    __shared__ float Ws[32][68];    // [kk][col], padded (16B-aligned rows)

    const int tid = threadIdx.x;
    const int tx = tid & 15;   // col group: cols 4*tx..4*tx+3
    const int ty = tid >> 4;   // row group: rows 8*ty..8*ty+7

    float acc[8][4];
    #pragma unroll
    for (int i = 0; i < 8; ++i)
        #pragma unroll
        for (int j = 0; j < 4; ++j) acc[i][j] = 0.f;

    for (int k0 = 0; k0 < 512; k0 += 32) {
        __syncthreads();
        // stage X tile (128 rows x 32 k) transposed into XsT
        #pragma unroll
        for (int it = 0; it < 4; ++it) {
            int u = tid + 256 * it;       // 0..1023
            int r = u >> 3, f = u & 7;
            float4 xv = *reinterpret_cast<const float4*>(&X[(size_t)(m0 + r) * 512 + k0 + 4 * f]);
            XsT[4 * f + 0][r] = xv.x;
            XsT[4 * f + 1][r] = xv.y;
            XsT[4 * f + 2][r] = xv.z;
            XsT[4 * f + 3][r] = xv.w;
        }
        // stage W tile (32 k x 64 cols)
        #pragma unroll
        for (int it = 0; it < 2; ++it) {
            int u = tid + 256 * it;       // 0..511
            int c4 = u & 15, kk = u >> 4;
            int c = c0 + 4 * c4;
            int h = c >> 5, dk = c & 31;
            float4 wv = *reinterpret_cast<const float4*>(&W[((size_t)h * 512 + k0 + kk) * 32 + dk]);
            *reinterpret_cast<float4*>(&Ws[kk][4 * c4]) = wv;
        }
        __syncthreads();
        #pragma unroll
        for (int kk = 0; kk < 32; ++kk) {
            float4 a0 = *reinterpret_cast<const float4*>(&XsT[kk][8 * ty]);
            float4 a1 = *reinterpret_cast<const float4*>(&XsT[kk][8 * ty + 4]);
            float4 bv = *reinterpret_cast<const float4*>(&Ws[kk][4 * tx]);
            float ar[8] = {a0.x, a0.y, a0.z, a0.w, a1.x, a1.y, a1.z, a1.w};
            float br[4] = {bv.x, bv.y, bv.z, bv.w};
            #pragma unroll
            for (int i = 0; i < 8; ++i)
                #pragma unroll
                for (int j = 0; j < 4; ++j) acc[i][j] = fmaf(ar[i], br[j], acc[i][j]);
        }
    }

    // epilogue: + bias, write to [B,H,N,DK]
    const int c = c0 + 4 * tx;
    const int h = c >> 5, dk = c & 31;
    float4 bq = *reinterpret_cast<const float4*>(&bias[h * 32 + dk]);
    #pragma unroll
    for (int i = 0; i < 8; ++i) {
        int m = m0 + 8 * ty + i;
        int bb = m >> 11, n = m & 2047;
        float4 ov;
        ov.x = acc[i][0] + bq.x;
        ov.y = acc[i][1] + bq.y;
        ov.z = acc[i][2] + bq.z;
        ov.w = acc[i][3] + bq.w;
        *reinterpret_cast<float4*>(&O[(((size_t)bb * 16 + h) * 2048 + n) * 32 + dk]) = ov;
    }
}

// ---------------------------------------------------------------------------
// Kernel 2: RBF-gated flash attention. 2-way j-split for occupancy:
// block = 256 threads = 128 query rows x 2 j-halves; each thread runs online
// softmax over its 1024-j half; halves merged once via LDS at the end.
// K[j], V[j], coords[j] reads are wave-uniform -> SMEM/L1 broadcast, no LDS
// staging in the main loop. Mask computed in rbf-space exactly like the
// reference (accurate expf, compare to 0.01/0.99).
// Writes pre[b,n,dk*16+h] (the reference's (DK,H) interleave) for out-proj.
// ---------------------------------------------------------------------------
__global__ __launch_bounds__(256) void attn_kernel(
    const float* __restrict__ Qws, const float* __restrict__ Kws, const float* __restrict__ Vws,
    const float* __restrict__ coords, const float* __restrict__ spreads,
    float* __restrict__ pre)
{
    const int b = blockIdx.z, h = blockIdx.y;
    const int tid = threadIdx.x;
    const int r = tid & 127;       // query row within block
    const int half = tid >> 7;     // j-half: 0 -> [0,1024), 1 -> [1024,2048)
    const int i = blockIdx.x * 128 + r;
    const int bh = b * 16 + h;

    const float sig = spreads[h];
    const float inv2s2 = 1.0f / (2.0f * sig * sig);
    const float scale = 0.17677669529663687f;   // 1/sqrt(32)

    const float* __restrict__ Cb = coords + (size_t)b * 2048 * 3;
    const float* __restrict__ Kb = Kws + (size_t)bh * 2048 * 32;
    const float* __restrict__ Vb = Vws + (size_t)bh * 2048 * 32;

    const float cix = Cb[(size_t)i * 3 + 0];
    const float ciy = Cb[(size_t)i * 3 + 1];
    const float ciz = Cb[(size_t)i * 3 + 2];

    float qf[32];
    #pragma unroll
    for (int u = 0; u < 8; ++u) {
        float4 t = *reinterpret_cast<const float4*>(&Qws[((size_t)bh * 2048 + i) * 32 + 4 * u]);
        qf[4 * u] = t.x; qf[4 * u + 1] = t.y; qf[4 * u + 2] = t.z; qf[4 * u + 3] = t.w;
    }

    float m = -INFINITY, l = 0.f;
    float o[32];
    #pragma unroll
    for (int kd = 0; kd < 32; ++kd) o[kd] = 0.f;

    const int jbeg = half * 1024;
    #pragma unroll 1
    for (int j0 = jbeg; j0 < jbeg + 1024; j0 += 16) {
        float sv[16];
        float mt = -INFINITY;
        #pragma unroll
        for (int jj = 0; jj < 16; ++jj) {
            const int j = j0 + jj;
            // wave-uniform coord read
            const float cjx = Cb[(size_t)j * 3 + 0];
            const float cjy = Cb[(size_t)j * 3 + 1];
            const float cjz = Cb[(size_t)j * 3 + 2];
            const float dx = cix - cjx;
            const float dy = ciy - cjy;
            const float dz = ciz - cjz;
            const float d2 = fmaf(dx, dx, fmaf(dy, dy, dz * dz));

            // wave-uniform K row
            const float* __restrict__ kp = Kb + (size_t)j * 32;
            float p0 = 0.f, p1 = 0.f, p2 = 0.f, p3 = 0.f;
            #pragma unroll
            for (int u = 0; u < 8; ++u) {
                const float4 kv = *reinterpret_cast<const float4*>(kp + 4 * u);
                p0 = fmaf(qf[4 * u + 0], kv.x, p0);
                p1 = fmaf(qf[4 * u + 1], kv.y, p1);
                p2 = fmaf(qf[4 * u + 2], kv.z, p2);
                p3 = fmaf(qf[4 * u + 3], kv.w, p3);
            }
            const float qk = (p0 + p1) + (p2 + p3);
            // accurate expf: mask domain matches the reference (rbf vs 0.01/0.99)
            const float rb = expf(-d2 * inv2s2);
            const bool valid = (rb >= 0.01f) && (rb <= 0.99f);
            const float sc = valid ? qk * scale * (rb * rb) : -1e9f;
            sv[jj] = sc;
            mt = fmaxf(mt, sc);
        }

        const float mn = fmaxf(m, mt);
        const float em = __expf(m - mn);
        l *= em;
        #pragma unroll
        for (int kd = 0; kd < 32; ++kd) o[kd] *= em;

        #pragma unroll
        for (int jj = 0; jj < 16; ++jj) {
            const int j = j0 + jj;
            const float p = __expf(sv[jj] - mn);
            l += p;
            const float* __restrict__ vp = Vb + (size_t)j * 32;
            #pragma unroll
            for (int u = 0; u < 8; ++u) {
                const float4 vv = *reinterpret_cast<const float4*>(vp + 4 * u);
                o[4 * u + 0] = fmaf(p, vv.x, o[4 * u + 0]);
                o[4 * u + 1] = fmaf(p, vv.y, o[4 * u + 1]);
                o[4 * u + 2] = fmaf(p, vv.z, o[4 * u + 2]);
                o[4 * u + 3] = fmaf(p, vv.w, o[4 * u + 3]);
            }
        }
        m = mn;
    }

    // ---- merge the two j-halves via LDS ----
    __shared__ float Lm[128];
    __shared__ float Ll[128];
    __shared__ float Lo[128][33];   // +1 pad: lane r, elem kd -> bank (r+kd)%32, conflict-free
    if (half == 1) {
        Lm[r] = m;
        Ll[r] = l;
        #pragma unroll
        for (int kd = 0; kd < 32; ++kd) Lo[r][kd] = o[kd];
    }
    __syncthreads();
    if (half == 0) {
        const float m1 = Lm[r];
        const float l1 = Ll[r];
        const float mn = fmaxf(m, m1);
        const float e0 = __expf(m - mn);
        const float e1 = __expf(m1 - mn);
        const float lt = fmaf(l, e0, l1 * e1);
        const float invl = 1.0f / lt;
        const size_t base = ((size_t)b * 2048 + i) * 512 + h;
        #pragma unroll
        for (int kd = 0; kd < 32; ++kd)
            pre[base + (size_t)kd * 16] = fmaf(o[kd], e0, Lo[r][kd] * e1) * invl;
    }
}

// ---------------------------------------------------------------------------
// Kernel 3: out = pre @ w_out^T.  Same GEMM structure as kernel 1;
// w_out staged transposed in LDS.
// ---------------------------------------------------------------------------
__global__ __launch_bounds__(256) void out_proj_kernel(
    const float* __restrict__ pre, const float* __restrict__ w_out,
    float* __restrict__ out)
{
    const int m0 = blockIdx.x * 128;
    const int d0 = blockIdx.y * 64;

    __shared__ float XsT[32][132];  // [ck][row]
    __shared__ float Bs[32][68];    // [ck][dcol]

    const int tid = threadIdx.x;
    const int tx = tid & 15;
    const int ty = tid >> 4;

    float acc[8][4];
    #pragma unroll
    for (int i = 0; i < 8; ++i)
        #pragma unroll
        for (int j = 0; j < 4; ++j) acc[i][j] = 0.f;

    for (int k0 = 0; k0 < 512; k0 += 32) {
        __syncthreads();
        #pragma unroll
        for (int it = 0; it < 4; ++it) {
            int u = tid + 256 * it;
            int r = u >> 3, f = u & 7;
            float4 xv = *reinterpret_cast<const float4*>(&pre[(size_t)(m0 + r) * 512 + k0 + 4 * f]);
            XsT[4 * f + 0][r] = xv.x;
            XsT[4 * f + 1][r] = xv.y;
            XsT[4 * f + 2][r] = xv.z;
            XsT[4 * f + 3][r] = xv.w;
        }
        #pragma unroll
        for (int it = 0; it < 2; ++it) {
            int u = tid + 256 * it;   // 0..511
            int dd = u >> 3, cf = u & 7;
            float4 wv = *reinterpret_cast<const float4*>(&w_out[(size_t)(d0 + dd) * 512 + k0 + 4 * cf]);
            Bs[4 * cf + 0][dd] = wv.x;
            Bs[4 * cf + 1][dd] = wv.y;
            Bs[4 * cf + 2][dd] = wv.z;
            Bs[4 * cf + 3][dd] = wv.w;
        }
        __syncthreads();
        #pragma unroll
        for (int kk = 0; kk < 32; ++kk) {
            float4 a0 = *reinterpret_cast<const float4*>(&XsT[kk][8 * ty]);
            float4 a1 = *reinterpret_cast<const float4*>(&XsT[kk][8 * ty + 4]);
            float4 bv = *reinterpret_cast<const float4*>(&Bs[kk][4 * tx]);
            float ar[8] = {a0.x, a0.y, a0.z, a0.w, a1.x, a1.y, a1.z, a1.w};
            float br[4] = {bv.x, bv.y, bv.z, bv.w};
            #pragma unroll
            for (int i = 0; i < 8; ++i)
                #pragma unroll
                for (int j = 0; j < 4; ++j) acc[i][j] = fmaf(ar[i], br[j], acc[i][j]);
        }
    }

    #pragma unroll
    for (int i = 0; i < 8; ++i) {
        int m = m0 + 8 * ty + i;
        float4 ov;
        ov.x = acc[i][0];
        ov.y = acc[i][1];
        ov.z = acc[i][2];
        ov.w = acc[i][3];
        *reinterpret_cast<float4*>(&out[(size_t)m * 512 + d0 + 4 * tx]) = ov;
    }
}

// ---------------------------------------------------------------------------
extern "C" void kernel_launch(void* const* d_in, const int* in_sizes, int n_in,
                              void* d_out, int out_size, void* d_ws, size_t ws_size,
                              hipStream_t stream) {
    const float* q       = (const float*)d_in[0];
    const float* k       = (const float*)d_in[1];
    const float* v       = (const float*)d_in[2];
    const float* coords  = (const float*)d_in[3];
    const float* q_proj  = (const float*)d_in[4];
    const float* k_proj  = (const float*)d_in[5];
    const float* v_proj  = (const float*)d_in[6];
    const float* q_bias  = (const float*)d_in[7];
    const float* k_bias  = (const float*)d_in[8];
    const float* v_bias  = (const float*)d_in[9];
    const float* w_out   = (const float*)d_in[10];
    const float* spreads = (const float*)d_in[11];
    float* out = (float*)d_out;

    // workspace layout (floats): Q | K | V | pre   (each B*H*N*DK = 2M, pre = B*N*D = 2M)
    float* Qws = (float*)d_ws;
    float* Kws = Qws + (size_t)Bb * Hh * Nn * DKk;
    float* Vws = Kws + (size_t)Bb * Hh * Nn * DKk;
    float* pre = Vws + (size_t)Bb * Hh * Nn * DKk;

    {
        dim3 grid(4096 / 128, 512 / 64, 3);
        qkv_proj_kernel<<<grid, 256, 0, stream>>>(q, k, v, q_proj, k_proj, v_proj,
                                                  q_bias, k_bias, v_bias, Qws, Kws, Vws);
    }
    {
        dim3 grid(Nn / 128, Hh, Bb);  // 2-way j-split: 128 rows/block
        attn_kernel<<<grid, 256, 0, stream>>>(Qws, Kws, Vws, coords, spreads, pre);
    }
    {
        dim3 grid(4096 / 128, 512 / 64);
        out_proj_kernel<<<grid, 256, 0, stream>>>(pre, w_out, out);
    }
}